// Round 1
// baseline (325.968 us; speedup 1.0000x reference)
//
#include <hip/hip_runtime.h>

typedef _Float16 half_t;
typedef _Float16 half8  __attribute__((ext_vector_type(8)));
typedef _Float16 half2v __attribute__((ext_vector_type(2)));
typedef float    floatx4 __attribute__((ext_vector_type(4)));

#define MFMA16(a, b, c) __builtin_amdgcn_mfma_f32_16x16x32_f16((a), (b), (c), 0, 0, 0)

// ---------------------------------------------------------------------------
// Prep: GMM Sigma_inv + det_scale (K=d=10). Thread k handles component k.
// ---------------------------------------------------------------------------
__global__ void k_prep_gmm(const float* __restrict__ raw, float* __restrict__ Sinv,
                           float* __restrict__ dets) {
    __shared__ float Li[10][10][10];
    const int t = threadIdx.x;
    if (t < 10) {
        const float* R = raw + t * 100;
        // unit lower-triangular inverse via forward substitution: L X = I
        for (int j = 0; j < 10; ++j) {
            for (int i = 0; i < 10; ++i) Li[t][i][j] = (i == j) ? 1.0f : 0.0f;
            for (int i = j + 1; i < 10; ++i) {
                float s = 0.0f;
                for (int m = j; m < i; ++m) s -= R[i * 10 + m] * Li[t][m][j];
                Li[t][i][j] = s;
            }
        }
        float Dl[10];
        float prod = 1.0f;
#pragma unroll
        for (int a = 0; a < 10; ++a) {
            float rd = R[a * 10 + a];
            float dv = rd * rd + 1e-4f;
            Dl[a] = 1.0f / dv;
            prod *= dv;
        }
        dets[t] = rsqrtf(prod);
        for (int i = 0; i < 10; ++i)
            for (int j = 0; j < 10; ++j) {
                float s = 0.0f;
#pragma unroll
                for (int a = 0; a < 10; ++a) s += Li[t][a][i] * Dl[a] * Li[t][a][j];
                Sinv[t * 100 + i * 10 + j] = s;
            }
    }
}

// ---------------------------------------------------------------------------
// Prep: conv2 weights fp32 [co][ci][tap] -> fp16 W2T[tap][co][ci]
// ---------------------------------------------------------------------------
__global__ void k_prep_w2t(const float* __restrict__ w2, half_t* __restrict__ W2T) {
    const int i = blockIdx.x * 256 + threadIdx.x;  // 18432 total
    if (i < 18432) {
        const int tap = i / 2048;
        const int r = i - tap * 2048;
        const int co = r >> 5;
        const int ci = r & 31;
        W2T[i] = (half_t)w2[(co * 32 + ci) * 9 + tap];
    }
}

// ---------------------------------------------------------------------------
// Prep: fc1 weights fp32 -> fp16 (same [n][k] layout)
// ---------------------------------------------------------------------------
__global__ void k_prep_w1h(const float* __restrict__ w, half_t* __restrict__ Wh) {
    const int i = blockIdx.x * 256 + threadIdx.x;  // 1179648 total
    if (i < 1179648) Wh[i] = (half_t)w[i];
}

// ---------------------------------------------------------------------------
// Fused conv1(fp32) + conv2(MFMA f16, tap-decomposed implicit GEMM)
//       + bias + ReLU + 2x2 maxpool. One block per image.
// h2p layout: [b][co*144 + Y*12 + X]  (matches reference flatten of [B,64,12,12])
// ---------------------------------------------------------------------------
__global__ __launch_bounds__(256, 2) void k_convs(
    const float* __restrict__ x, const float* __restrict__ w1,
    const float* __restrict__ b1, const float* __restrict__ b2,
    const half_t* __restrict__ W2T, half_t* __restrict__ h2p) {
    __shared__ float s_x[784];
    __shared__ float s_w1[288];
    __shared__ float s_b1[32];
    __shared__ float s_b2[64];
    __shared__ __align__(16) half_t s_h1[4][26][26][8];  // [ci/8][y][x][ci%8]

    const int t = threadIdx.x;
    const int b = blockIdx.x;

    for (int i = t; i < 784; i += 256) s_x[i] = x[(size_t)b * 784 + i];
    for (int i = t; i < 288; i += 256) s_w1[i] = w1[i];
    if (t < 32) s_b1[t] = b1[t];
    if (t < 64) s_b2[t] = b2[t];
    __syncthreads();

    // ---- conv1: wave g owns ci-group g (8 channels), lanes sweep pixels ----
    {
        const int g = t >> 6;
        const int u = t & 63;
        float wr[8][9], br[8];
#pragma unroll
        for (int j = 0; j < 8; ++j) {
            br[j] = s_b1[g * 8 + j];
#pragma unroll
            for (int k = 0; k < 9; ++k) wr[j][k] = s_w1[(g * 8 + j) * 9 + k];
        }
        for (int p = u; p < 676; p += 64) {
            const int yy = p / 26;
            const int xx = p - yy * 26;
            float win[9];
#pragma unroll
            for (int r = 0; r < 3; ++r)
#pragma unroll
                for (int c = 0; c < 3; ++c) win[r * 3 + c] = s_x[(yy + r) * 28 + xx + c];
            half8 hv;
#pragma unroll
            for (int j = 0; j < 8; ++j) {
                float a = br[j];
#pragma unroll
                for (int k = 0; k < 9; ++k) a = fmaf(win[k], wr[j][k], a);
                hv[j] = (half_t)fmaxf(a, 0.0f);
            }
            *(half8*)(&s_h1[g][yy][xx][0]) = hv;
        }
    }
    __syncthreads();

    // ---- conv2: wave w owns M-band (9 tiles of 2y x 8x), all 64 co ----
    const int w = t >> 6;
    const int ln = t & 63;
    const int n16 = ln & 15;
    const int q = ln >> 4;
    const int dy = (ln >> 3) & 1;  // A-row role: r = ln&15 -> (dy,dx)
    const int dx = ln & 7;

    half8 bf[9][4];  // B-frags: [tap][co-tile], held in registers
#pragma unroll
    for (int tap = 0; tap < 9; ++tap)
#pragma unroll
        for (int ct = 0; ct < 4; ++ct)
            bf[tap][ct] = *(const half8*)(W2T + ((tap * 64 + ct * 16 + n16) * 32 + q * 8));

    for (int i = 0; i < 9; ++i) {
        const int mt = w * 9 + i;
        const int ty = mt / 3;
        const int tx = mt - ty * 3;
        const int y0 = 2 * ty, x0 = 8 * tx;
        floatx4 acc[4];
#pragma unroll
        for (int ct = 0; ct < 4; ++ct) acc[ct] = (floatx4){0.f, 0.f, 0.f, 0.f};
#pragma unroll
        for (int tap = 0; tap < 9; ++tap) {
            const int ky = tap / 3;
            const int kx = tap - ky * 3;
            half8 af = *(const half8*)(&s_h1[q][y0 + dy + ky][x0 + dx + kx][0]);
#pragma unroll
            for (int ct = 0; ct < 4; ++ct) acc[ct] = MFMA16(af, bf[tap][ct], acc[ct]);
        }
        // epilogue: 2x2 maxpool + bias + relu. C row m=q*4+reg: q^2 is dy partner.
#pragma unroll
        for (int ct = 0; ct < 4; ++ct) {
            float p0 = fmaxf(acc[ct][0], acc[ct][1]);
            float p1 = fmaxf(acc[ct][2], acc[ct][3]);
            p0 = fmaxf(p0, __shfl_xor(p0, 32, 64));
            p1 = fmaxf(p1, __shfl_xor(p1, 32, 64));
            if (q < 2) {
                const int co = ct * 16 + n16;
                const float bb = s_b2[co];
                half2v hz;
                hz[0] = (half_t)fmaxf(p0 + bb, 0.0f);
                hz[1] = (half_t)fmaxf(p1 + bb, 0.0f);
                *(half2v*)(h2p + (size_t)b * 9216 + co * 144 + ty * 12 + 4 * tx + 2 * q) = hz;
            }
        }
    }
}

// ---------------------------------------------------------------------------
// fc1: C[4096,128] = A[4096,9216](fp16) x W^T, split-K=8, fp32 partials.
// Block: M-tile 128, N=128 full, K-chunk 1152. Wave w owns rows w*32..+32.
// ---------------------------------------------------------------------------
__global__ __launch_bounds__(256) void k_fc1(const half_t* __restrict__ A,
                                             const half_t* __restrict__ W,
                                             float* __restrict__ part) {
    __shared__ __align__(16) half_t sA[128][32];
    const int t = threadIdx.x;
    const int mb = blockIdx.x;  // 0..31
    const int kb = blockIdx.y;  // 0..7
    const int w = t >> 6, ln = t & 63, n16 = ln & 15, q = ln >> 4;
    const int sm = t >> 2;
    const int sk = (t & 3) * 8;

    const half_t* gA = A + (size_t)(mb * 128 + sm) * 9216 + sk;

    floatx4 acc[2][8];
#pragma unroll
    for (int s = 0; s < 2; ++s)
#pragma unroll
        for (int nt = 0; nt < 8; ++nt) acc[s][nt] = (floatx4){0.f, 0.f, 0.f, 0.f};

    for (int kt = 0; kt < 36; ++kt) {
        const int k0 = kb * 1152 + kt * 32;
        __syncthreads();
        *(half8*)(&sA[sm][sk]) = *(const half8*)(gA + k0);
        *(half8*)(&sA[sm + 64][sk]) = *(const half8*)(gA + (size_t)64 * 9216 + k0);
        __syncthreads();
        half8 af0 = *(const half8*)(&sA[w * 32 + n16][q * 8]);
        half8 af1 = *(const half8*)(&sA[w * 32 + 16 + n16][q * 8]);
#pragma unroll
        for (int nt = 0; nt < 8; ++nt) {
            half8 bfr = *(const half8*)(W + (size_t)(nt * 16 + n16) * 9216 + k0 + q * 8);
            acc[0][nt] = MFMA16(af0, bfr, acc[0][nt]);
            acc[1][nt] = MFMA16(af1, bfr, acc[1][nt]);
        }
    }
    const int rowbase = mb * 128 + w * 32;
#pragma unroll
    for (int s = 0; s < 2; ++s)
#pragma unroll
        for (int nt = 0; nt < 8; ++nt)
#pragma unroll
            for (int r = 0; r < 4; ++r) {
                const int row = rowbase + s * 16 + q * 4 + r;
                const int col = nt * 16 + n16;
                part[(size_t)kb * 524288 + (size_t)row * 128 + col] = acc[s][nt][r];
            }
}

// ---------------------------------------------------------------------------
// fc1 split-K reduction + bias + ReLU -> fp16 h3
// ---------------------------------------------------------------------------
__global__ void k_fc1red(const float* __restrict__ part, const float* __restrict__ b,
                         half_t* __restrict__ h3) {
    const int idx = blockIdx.x * 256 + threadIdx.x;  // 524288 exact
    const int col = idx & 127;
    float s = 0.0f;
#pragma unroll
    for (int j = 0; j < 8; ++j) s += part[(size_t)j * 524288 + idx];
    s = fmaxf(s + b[col], 0.0f);
    h3[idx] = (half_t)s;
}

// ---------------------------------------------------------------------------
// fc2 + GMM posterior (fp32). One thread per sample.
// ---------------------------------------------------------------------------
__global__ __launch_bounds__(256) void k_fc2gmm(
    const half_t* __restrict__ h3, const float* __restrict__ fw,
    const float* __restrict__ fb, const float* __restrict__ cent,
    const float* __restrict__ Sinv, const float* __restrict__ dets,
    float* __restrict__ out) {
    __shared__ float sw[1280];
    __shared__ float sb[10];
    __shared__ float sc[100];
    __shared__ float ss[1000];
    __shared__ float sd[10];
    const int t = threadIdx.x;
    for (int i = t; i < 1280; i += 256) sw[i] = fw[i];
    if (t < 10) sb[t] = fb[t];
    if (t < 100) sc[t] = cent[t];
    for (int i = t; i < 1000; i += 256) ss[i] = Sinv[i];
    if (t < 10) sd[t] = dets[t];
    __syncthreads();

    const int bidx = blockIdx.x * 256 + t;  // 4096 samples exact
    half2v hh[64];
    const half2v* hp = (const half2v*)(h3 + (size_t)bidx * 128);
#pragma unroll
    for (int i = 0; i < 64; ++i) hh[i] = hp[i];

    float y[10];
#pragma unroll
    for (int o = 0; o < 10; ++o) {
        float a = sb[o];
#pragma unroll
        for (int k = 0; k < 64; ++k) {
            a = fmaf((float)hh[k][0], sw[o * 128 + 2 * k], a);
            a = fmaf((float)hh[k][1], sw[o * 128 + 2 * k + 1], a);
        }
        y[o] = a;
    }

    float expo[10];
    float mx = -3.402823466e38f;
#pragma unroll
    for (int k = 0; k < 10; ++k) {
        float d[10];
#pragma unroll
        for (int j = 0; j < 10; ++j) d[j] = y[j] - sc[k * 10 + j];
        float s = 0.0f;
#pragma unroll
        for (int i = 0; i < 10; ++i) {
            float r = 0.0f;
#pragma unroll
            for (int j = 0; j < 10; ++j) r = fmaf(ss[k * 100 + i * 10 + j], d[j], r);
            s = fmaf(d[i], r, s);
        }
        expo[k] = -0.5f * s;
        mx = fmaxf(mx, expo[k]);
    }
    float num[10];
    float sum = 0.0f;
#pragma unroll
    for (int k = 0; k < 10; ++k) {
        num[k] = sd[k] * __expf(expo[k] - mx);
        sum += num[k];
    }
    const float inv = 1.0f / sum;
#pragma unroll
    for (int k = 0; k < 10; ++k) out[(size_t)bidx * 10 + k] = num[k] * inv;
}

// ---------------------------------------------------------------------------
extern "C" void kernel_launch(void* const* d_in, const int* in_sizes, int n_in,
                              void* d_out, int out_size, void* d_ws, size_t ws_size,
                              hipStream_t stream) {
    const float* x = (const float*)d_in[0];
    const float* w1 = (const float*)d_in[1];
    const float* b1 = (const float*)d_in[2];
    const float* w2 = (const float*)d_in[3];
    const float* b2 = (const float*)d_in[4];
    const float* fw1 = (const float*)d_in[5];
    const float* fb1 = (const float*)d_in[6];
    const float* fw2 = (const float*)d_in[7];
    const float* fb2 = (const float*)d_in[8];
    const float* cen = (const float*)d_in[9];
    const float* raw = (const float*)d_in[10];
    float* out = (float*)d_out;

    char* ws = (char*)d_ws;
    half_t* W2T = (half_t*)(ws);                 //    36,864 B
    half_t* W1h = (half_t*)(ws + 36864);         // 2,359,296 B
    half_t* h2p = (half_t*)(ws + 2396160);       // 75,497,472 B
    float* part = (float*)(ws + 77893632);       // 16,777,216 B
    half_t* h3h = (half_t*)(ws + 94670848);      // 1,048,576 B
    float* gS = (float*)(ws + 95719424);         //     4,000 B
    float* gD = (float*)(ws + 95723424);         //        40 B  (total ~95.7 MB)

    k_prep_gmm<<<1, 64, 0, stream>>>(raw, gS, gD);
    k_prep_w2t<<<72, 256, 0, stream>>>(w2, W2T);
    k_prep_w1h<<<4608, 256, 0, stream>>>(fw1, W1h);
    k_convs<<<4096, 256, 0, stream>>>(x, w1, b1, b2, W2T, h2p);
    k_fc1<<<dim3(32, 8), 256, 0, stream>>>(h2p, W1h, part);
    k_fc1red<<<2048, 256, 0, stream>>>(part, fb1, h3h);
    k_fc2gmm<<<16, 256, 0, stream>>>(h3h, fw2, fb2, cen, gS, gD, out);
}